// Round 1
// baseline (23410.666 us; speedup 1.0000x reference)
//
#include <hip/hip_runtime.h>
#include <math.h>

#define TB 256   // batch
#define TD 131   // input/output feature dim
#define TH 256   // hidden
#define T_OUT 256

// LSTM cell step: z = bias + x@Wih^T + h_old@Whh^T ; gates; c updated in
// place; h_new written to separate buffer (ping-pong).
// grid: (TH/16, TB/16), block 256.  Thread (tx,ty) owns (b=b0+ty, j=j0+tx),
// all 4 gates. LDS W layout: Ws[kk][r'] with r' = j_local*4 + gate so the 4
// gate weights are one float4 (one ds_read_b128). Stride 68 floats = 272B
// (16B aligned for float4; reads ~2-way banked).
__global__ __launch_bounds__(256) void lstm_step(
    const float* __restrict__ x, int xK,
    const float* __restrict__ h_old,
    float* __restrict__ c,
    const float* __restrict__ Wih,
    const float* __restrict__ Whh,
    const float* __restrict__ bih,
    const float* __restrict__ bhh,
    float* __restrict__ h_new)
{
    __shared__ __align__(16) float As[16 * 33];
    __shared__ __align__(16) float Ws[32 * 68];
    const int tid = threadIdx.x;
    const int tx = tid & 15;
    const int ty = tid >> 4;
    const int j0 = blockIdx.x * 16;
    const int b0 = blockIdx.y * 16;

    float acc0 = 0.f, acc1 = 0.f, acc2 = 0.f, acc3 = 0.f;

    for (int pass = 0; pass < 2; ++pass) {
        const float* A = pass ? h_old : x;
        const float* W = pass ? Whh : Wih;
        const int K = pass ? TH : xK;
        for (int k0 = 0; k0 < K; k0 += 32) {
            // stage A tile: As[r][kk], r in [0,16), kk in [0,32)
            #pragma unroll
            for (int i = 0; i < 2; ++i) {
                int e = i * 256 + tid;
                int r = e >> 5, kk = e & 31;
                int k = k0 + kk;
                As[r * 33 + kk] = (k < K) ? A[(size_t)(b0 + r) * K + k] : 0.f;
            }
            // stage W tile: Ws[kk][rp], rp = jl*4 + gi, global row = gi*TH + j0 + jl
            #pragma unroll
            for (int i = 0; i < 8; ++i) {
                int e = i * 256 + tid;
                int rp = e >> 5, kk = e & 31;
                int jl = rp >> 2, gi = rp & 3;
                int k = k0 + kk;
                Ws[kk * 68 + rp] =
                    (k < K) ? W[(size_t)(gi * TH + j0 + jl) * K + k] : 0.f;
            }
            __syncthreads();
            #pragma unroll
            for (int kk = 0; kk < 32; ++kk) {
                float4 w = *reinterpret_cast<const float4*>(&Ws[kk * 68 + tx * 4]);
                float a = As[ty * 33 + kk];
                acc0 = fmaf(a, w.x, acc0);
                acc1 = fmaf(a, w.y, acc1);
                acc2 = fmaf(a, w.z, acc2);
                acc3 = fmaf(a, w.w, acc3);
            }
            __syncthreads();
        }
    }

    const int b = b0 + ty, j = j0 + tx;
    float zi = acc0 + bih[0 * TH + j] + bhh[0 * TH + j];
    float zf = acc1 + bih[1 * TH + j] + bhh[1 * TH + j];
    float zg = acc2 + bih[2 * TH + j] + bhh[2 * TH + j];
    float zo = acc3 + bih[3 * TH + j] + bhh[3 * TH + j];

    float ig = 1.f / (1.f + expf(-zi));
    float fg = 1.f / (1.f + expf(-zf));
    float gg = tanhf(zg);
    float og = 1.f / (1.f + expf(-zo));
    float cold = c[b * TH + j];
    float cnew = fg * cold + ig * gg;
    c[b * TH + j] = cnew;
    h_new[b * TH + j] = og * tanhf(cnew);
}

// logits = h1 @ lin_W^T + lin_b ; out = log_softmax(logits) over 131 classes.
// one block per batch row.
__global__ __launch_bounds__(256) void emit_kernel(
    const float* __restrict__ h1,
    const float* __restrict__ linW,
    const float* __restrict__ linb,
    float* __restrict__ out)
{
    __shared__ float sh[TH];
    __shared__ float red[256];
    const int b = blockIdx.x;
    const int tid = threadIdx.x;
    sh[tid] = h1[b * TH + tid];
    __syncthreads();

    float logit = 0.f;
    if (tid < TD) {
        const float* w = &linW[(size_t)tid * TH];
        float acc = 0.f;
        #pragma unroll 4
        for (int k = 0; k < TH; k += 4) {
            float4 wv = *reinterpret_cast<const float4*>(&w[k]);
            acc = fmaf(sh[k + 0], wv.x, acc);
            acc = fmaf(sh[k + 1], wv.y, acc);
            acc = fmaf(sh[k + 2], wv.z, acc);
            acc = fmaf(sh[k + 3], wv.w, acc);
        }
        logit = acc + linb[tid];
    }

    red[tid] = (tid < TD) ? logit : -INFINITY;
    __syncthreads();
    for (int s = 128; s > 0; s >>= 1) {
        if (tid < s) red[tid] = fmaxf(red[tid], red[tid + s]);
        __syncthreads();
    }
    float m = red[0];
    __syncthreads();
    red[tid] = (tid < TD) ? expf(logit - m) : 0.f;
    __syncthreads();
    for (int s = 128; s > 0; s >>= 1) {
        if (tid < s) red[tid] += red[tid + s];
        __syncthreads();
    }
    float lse = m + logf(red[0]);
    if (tid < TD) out[(size_t)b * TD + tid] = logit - lse;
}

extern "C" void kernel_launch(void* const* d_in, const int* in_sizes, int n_in,
                              void* d_out, int out_size, void* d_ws, size_t ws_size,
                              hipStream_t stream) {
    const float* X     = (const float*)d_in[0];
    const float* Y     = (const float*)d_in[1];
    const float* eWih0 = (const float*)d_in[2];
    const float* eWhh0 = (const float*)d_in[3];
    const float* ebih0 = (const float*)d_in[4];
    const float* ebhh0 = (const float*)d_in[5];
    const float* eWih1 = (const float*)d_in[6];
    const float* eWhh1 = (const float*)d_in[7];
    const float* ebih1 = (const float*)d_in[8];
    const float* ebhh1 = (const float*)d_in[9];
    const float* dWih0 = (const float*)d_in[10];
    const float* dWhh0 = (const float*)d_in[11];
    const float* dbih0 = (const float*)d_in[12];
    const float* dbhh0 = (const float*)d_in[13];
    const float* dWih1 = (const float*)d_in[14];
    const float* dWhh1 = (const float*)d_in[15];
    const float* dbih1 = (const float*)d_in[16];
    const float* dbhh1 = (const float*)d_in[17];
    const float* linW  = (const float*)d_in[18];
    const float* linb  = (const float*)d_in[19];
    float* out = (float*)d_out;
    float* ws  = (float*)d_ws;

    // ws layout (floats): h0[2], h1[2], c0, c1  -- 6 x 65536
    float* h0[2] = { ws,              ws + 1 * 65536 };
    float* h1[2] = { ws + 2 * 65536,  ws + 3 * 65536 };
    float* c0 = ws + 4 * 65536;
    float* c1 = ws + 5 * 65536;
    hipMemsetAsync(ws, 0, 6 * 65536 * sizeof(float), stream);

    dim3 grid(TH / 16, TB / 16);
    dim3 blk(256);
    int cur = 0;

    // encoder over X[0..255]
    for (int t = 0; t < 256; ++t) {
        lstm_step<<<grid, blk, 0, stream>>>(X + (size_t)t * TB * TD, TD,
                                            h0[cur], c0, eWih0, eWhh0, ebih0, ebhh0,
                                            h0[cur ^ 1]);
        lstm_step<<<grid, blk, 0, stream>>>(h0[cur ^ 1], TH,
                                            h1[cur], c1, eWih1, eWhh1, ebih1, ebhh1,
                                            h1[cur ^ 1]);
        cur ^= 1;
    }
    // decoder: inputs [X[256], Y[0..254]]
    for (int t = 0; t < T_OUT; ++t) {
        const float* xin = (t == 0) ? (X + (size_t)256 * TB * TD)
                                    : (Y + (size_t)(t - 1) * TB * TD);
        lstm_step<<<grid, blk, 0, stream>>>(xin, TD,
                                            h0[cur], c0, dWih0, dWhh0, dbih0, dbhh0,
                                            h0[cur ^ 1]);
        lstm_step<<<grid, blk, 0, stream>>>(h0[cur ^ 1], TH,
                                            h1[cur], c1, dWih1, dWhh1, dbih1, dbhh1,
                                            h1[cur ^ 1]);
        emit_kernel<<<dim3(TB), blk, 0, stream>>>(h1[cur ^ 1], linW, linb,
                                                  out + (size_t)t * TB * TD);
        cur ^= 1;
    }
}